// Round 1
// baseline (6948.322 us; speedup 1.0000x reference)
//
#include <hip/hip_runtime.h>
#include <hip/hip_bf16.h>

#define NN 50000
#define NE 800000
#define MPAD 50048   // 391 * 128

typedef __attribute__((ext_vector_type(8))) short short8;
typedef __attribute__((ext_vector_type(4))) float f32x4;
typedef __attribute__((ext_vector_type(4))) unsigned short us4;
typedef __attribute__((ext_vector_type(8))) unsigned short us8;

static __device__ __forceinline__ unsigned short f2bf(float f) {
    union { float f; unsigned int u; } v; v.f = f;
    unsigned int u = v.u;
    return (unsigned short)((u + 0x7FFFu + ((u >> 16) & 1u)) >> 16);  // RNE
}

__global__ void k_deg(const int* __restrict__ src, const int* __restrict__ dst,
                      int* __restrict__ degO, int* __restrict__ degI) {
    int i = blockIdx.x * 256 + threadIdx.x;
    if (i < NE) {
        atomicAdd(&degO[src[i]], 1);
        atomicAdd(&degI[dst[i]], 1);
    }
}

__global__ void k_norm(const int* __restrict__ degO, const int* __restrict__ degI,
                       float* __restrict__ nS, float* __restrict__ nD) {
    int i = blockIdx.x * 256 + threadIdx.x;
    if (i < NN) {
        int o = degO[i], d = degI[i];
        nS[i] = 1.0f / sqrtf((float)(o > 0 ? o : 1));
        nD[i] = 1.0f / sqrtf((float)(d > 0 ? d : 1));
    }
}

__global__ void k_cvtW(const float* __restrict__ W, unsigned short* __restrict__ Wb, int n) {
    int i = blockIdx.x * 256 + threadIdx.x;
    if (i < n) Wb[i] = f2bf(W[i]);
}

// feats * norm_src -> bf16, pad rows zeroed. grid = MPAD, block = 256
__global__ void k_cvt0(const float* __restrict__ x, const float* __restrict__ nS,
                       unsigned short* __restrict__ xb) {
    int row = blockIdx.x; int t = threadIdx.x;
    if (row < NN) {
        float s = nS[row];
        xb[(long)row * 256 + t] = f2bf(x[(long)row * 256 + t] * s);
    } else {
        xb[(long)row * 256 + t] = 0;
    }
}

// A [MPAD][256] bf16 row-major, B [256][NOUT] bf16 row-major, C [MPAD][NOUT] f32.
// 128x128 tile, 4 waves in 2x2, each wave 64x64 = 4x4 frags of 16x16x32 MFMA.
template<int NOUT>
__global__ __launch_bounds__(256) void k_gemm(const unsigned short* __restrict__ A,
                                              const unsigned short* __restrict__ B,
                                              float* __restrict__ C) {
    __shared__ unsigned short As[128][40];
    __shared__ unsigned short Bs[128][40];   // stored transposed: Bs[col][k]
    const int bm = blockIdx.x * 128;
    const int bn = blockIdx.y * 128;
    const int tid = threadIdx.x;
    const int lane = tid & 63;
    const int w = tid >> 6;
    const int wr = w >> 1, wc = w & 1;

    f32x4 acc[4][4];
#pragma unroll
    for (int m = 0; m < 4; m++)
#pragma unroll
        for (int n = 0; n < 4; n++) acc[m][n] = (f32x4){0.f, 0.f, 0.f, 0.f};

    for (int kt = 0; kt < 256; kt += 32) {
        // stage A: 128 rows x 32 k. thread t: row t>>1, 16 ushorts at c=(t&1)*16
        {
            int r = tid >> 1, c = (tid & 1) * 16;
            const unsigned short* g = &A[(long)(bm + r) * 256 + kt + c];
            *(us8*)&As[r][c]     = *(const us8*)(g);
            *(us8*)&As[r][c + 8] = *(const us8*)(g + 8);
        }
        // stage B transposed: thread t: k=t>>3, cols (t&7)*16 .. +15
        {
            int k = tid >> 3, c0 = (tid & 7) * 16;
            const unsigned short* g = &B[(long)(kt + k) * NOUT + bn + c0];
            us8 v0 = *(const us8*)(g);
            us8 v1 = *(const us8*)(g + 8);
#pragma unroll
            for (int j = 0; j < 8; j++) Bs[c0 + j][k] = v0[j];
#pragma unroll
            for (int j = 0; j < 8; j++) Bs[c0 + 8 + j][k] = v1[j];
        }
        __syncthreads();

        union U { us4 h[2]; short8 s; };
        const int kb = (lane >> 4) * 4;
        short8 af[4], bf[4];
#pragma unroll
        for (int m = 0; m < 4; m++) {
            int r = wr * 64 + m * 16 + (lane & 15);
            U u; u.h[0] = *(const us4*)&As[r][kb]; u.h[1] = *(const us4*)&As[r][kb + 16];
            af[m] = u.s;
        }
#pragma unroll
        for (int n = 0; n < 4; n++) {
            int cidx = wc * 64 + n * 16 + (lane & 15);
            U u; u.h[0] = *(const us4*)&Bs[cidx][kb]; u.h[1] = *(const us4*)&Bs[cidx][kb + 16];
            bf[n] = u.s;
        }
#pragma unroll
        for (int m = 0; m < 4; m++)
#pragma unroll
            for (int n = 0; n < 4; n++)
                acc[m][n] = __builtin_amdgcn_mfma_f32_16x16x32_bf16(af[m], bf[n], acc[m][n], 0, 0, 0);
        __syncthreads();
    }

    // epilogue: D col = lane&15, row = (lane>>4)*4 + reg
#pragma unroll
    for (int m = 0; m < 4; m++) {
        int rbase = bm + wr * 64 + m * 16 + (lane >> 4) * 4;
#pragma unroll
        for (int n = 0; n < 4; n++) {
            int cidx = bn + wc * 64 + n * 16 + (lane & 15);
#pragma unroll
            for (int j = 0; j < 4; j++)
                C[(long)(rbase + j) * NOUT + cidx] = acc[m][n][j];
        }
    }
}

// one wave per edge: gather hg[src] row, atomicAdd into macc[dst] row
template<int F>
__global__ void k_scatter(const int* __restrict__ src, const int* __restrict__ dst,
                          const float* __restrict__ hg, float* __restrict__ macc) {
    int e = blockIdx.x * 4 + (threadIdx.x >> 6);
    int lane = threadIdx.x & 63;
    if (e >= NE) return;
    int s = src[e], d = dst[e];
    if (F == 256) {
        float4 v = *(const float4*)&hg[(long)s * F + lane * 4];
        float* o = &macc[(long)d * F + lane * 4];
        atomicAdd(o + 0, v.x); atomicAdd(o + 1, v.y);
        atomicAdd(o + 2, v.z); atomicAdd(o + 3, v.w);
    } else {
        if (lane < F / 4) {
            float4 v = *(const float4*)&hg[(long)s * F + lane * 4];
            float* o = &macc[(long)d * F + lane * 4];
            atomicAdd(o + 0, v.x); atomicAdd(o + 1, v.y);
            atomicAdd(o + 2, v.z); atomicAdd(o + 3, v.w);
        }
    }
}

// out = macc*nD + b (+relu); optionally duplicate to out2; optionally produce next xb
template<int F, bool RELU, bool NEXT>
__global__ void k_final(const float* __restrict__ macc, const float* __restrict__ nD,
                        const float* __restrict__ nS, const float* __restrict__ b,
                        float* __restrict__ out, float* __restrict__ out2,
                        unsigned short* __restrict__ xb) {
    int row = blockIdx.x;
    int t = threadIdx.x;  // F threads
    if (row < NN) {
        float v = macc[(long)row * F + t] * nD[row] + b[t];
        if (RELU) v = fmaxf(v, 0.f);
        out[(long)row * F + t] = v;
        if (out2) out2[(long)row * F + t] = v;
        if (NEXT) xb[(long)row * 256 + t] = f2bf(v * nS[row]);
    } else {
        if (NEXT) xb[(long)row * 256 + t] = 0;
    }
}

extern "C" void kernel_launch(void* const* d_in, const int* in_sizes, int n_in,
                              void* d_out, int out_size, void* d_ws, size_t ws_size,
                              hipStream_t stream) {
    const float* feats = (const float*)d_in[0];
    const int*   src   = (const int*)d_in[1];
    const int*   dst   = (const int*)d_in[2];
    const float* W0 = (const float*)d_in[3];
    const float* b0 = (const float*)d_in[4];
    const float* W1 = (const float*)d_in[5];
    const float* b1 = (const float*)d_in[6];
    const float* W2 = (const float*)d_in[7];
    const float* b2 = (const float*)d_in[8];

    float* out = (float*)d_out;
    float* h0  = out;
    float* h1  = out + (long)NN * 256;
    float* h2  = out + 2L * NN * 256;
    float* h2b = out + 2L * NN * 256 + (long)NN * 128;

    char* ws = (char*)d_ws;
    size_t off = 0;
    auto alloc = [&](size_t bytes) { void* p = ws + off; off += (bytes + 255) & ~255UL; return p; };
    unsigned short* xb  = (unsigned short*)alloc((size_t)MPAD * 256 * 2);
    float* hg   = (float*)alloc((size_t)MPAD * 256 * 4);
    float* macc = (float*)alloc((size_t)NN * 256 * 4);
    unsigned short* W0b = (unsigned short*)alloc(256 * 256 * 2);
    unsigned short* W1b = (unsigned short*)alloc(256 * 256 * 2);
    unsigned short* W2b = (unsigned short*)alloc(256 * 128 * 2);
    int*   degO = (int*)alloc(NN * 4);
    int*   degI = (int*)alloc(NN * 4);
    float* nS   = (float*)alloc(NN * 4);
    float* nD   = (float*)alloc(NN * 4);

    // degrees + norms
    hipMemsetAsync(degO, 0, NN * 4, stream);
    hipMemsetAsync(degI, 0, NN * 4, stream);
    k_deg<<<(NE + 255) / 256, 256, 0, stream>>>(src, dst, degO, degI);
    k_norm<<<(NN + 255) / 256, 256, 0, stream>>>(degO, degI, nS, nD);

    // weight conversion
    k_cvtW<<<(256 * 256 + 255) / 256, 256, 0, stream>>>(W0, W0b, 256 * 256);
    k_cvtW<<<(256 * 256 + 255) / 256, 256, 0, stream>>>(W1, W1b, 256 * 256);
    k_cvtW<<<(256 * 128 + 255) / 256, 256, 0, stream>>>(W2, W2b, 256 * 128);

    // layer 0 input
    k_cvt0<<<MPAD, 256, 0, stream>>>(feats, nS, xb);

    // ---- layer 0 ----
    k_gemm<256><<<dim3(MPAD / 128, 2), 256, 0, stream>>>(xb, W0b, hg);
    hipMemsetAsync(macc, 0, (size_t)NN * 256 * 4, stream);
    k_scatter<256><<<NE / 4, 256, 0, stream>>>(src, dst, hg, macc);
    k_final<256, true, true><<<MPAD, 256, 0, stream>>>(macc, nD, nS, b0, h0, nullptr, xb);

    // ---- layer 1 ----
    k_gemm<256><<<dim3(MPAD / 128, 2), 256, 0, stream>>>(xb, W1b, hg);
    hipMemsetAsync(macc, 0, (size_t)NN * 256 * 4, stream);
    k_scatter<256><<<NE / 4, 256, 0, stream>>>(src, dst, hg, macc);
    k_final<256, true, true><<<MPAD, 256, 0, stream>>>(macc, nD, nS, b1, h1, nullptr, xb);

    // ---- layer 2 ----
    k_gemm<128><<<dim3(MPAD / 128, 1), 256, 0, stream>>>(xb, W2b, hg);
    hipMemsetAsync(macc, 0, (size_t)NN * 128 * 4, stream);
    k_scatter<128><<<NE / 4, 256, 0, stream>>>(src, dst, hg, macc);
    k_final<128, false, false><<<NN, 128, 0, stream>>>(macc, nD, nS, b2, h2, h2b, nullptr);
}

// Round 2
// 549.538 us; speedup vs baseline: 12.6439x; 12.6439x over previous
//
#include <hip/hip_runtime.h>
#include <hip/hip_bf16.h>

#define NN 50000
#define NE 800000
#define MPAD 50048   // 391 * 128
#define NBLK 196     // ceil(NN/256)

typedef __attribute__((ext_vector_type(8))) short short8;
typedef __attribute__((ext_vector_type(4))) float f32x4;
typedef __attribute__((ext_vector_type(2))) float f32x2;
typedef __attribute__((ext_vector_type(4))) unsigned short us4;
typedef __attribute__((ext_vector_type(8))) unsigned short us8;

static __device__ __forceinline__ unsigned short f2bf(float f) {
    union { float f; unsigned int u; } v; v.f = f;
    unsigned int u = v.u;
    return (unsigned short)((u + 0x7FFFu + ((u >> 16) & 1u)) >> 16);  // RNE
}

// ---------------- degrees / norms ----------------
__global__ void k_deg(const int* __restrict__ src, const int* __restrict__ dst,
                      int* __restrict__ degO, int* __restrict__ degI) {
    int i = blockIdx.x * 256 + threadIdx.x;
    if (i < NE) {
        atomicAdd(&degO[src[i]], 1);
        atomicAdd(&degI[dst[i]], 1);
    }
}

__global__ void k_norm(const int* __restrict__ degO, const int* __restrict__ degI,
                       float* __restrict__ nS, float* __restrict__ nD) {
    int i = blockIdx.x * 256 + threadIdx.x;
    if (i < NN) {
        int o = degO[i], d = degI[i];
        nS[i] = 1.0f / sqrtf((float)(o > 0 ? o : 1));
        nD[i] = 1.0f / sqrtf((float)(d > 0 ? d : 1));
    }
}

// ---------------- CSR build: hierarchical exclusive scan + counting sort ----------------
static __device__ __forceinline__ int wave_iscan(int v, int lane) {
#pragma unroll
    for (int o = 1; o < 64; o <<= 1) {
        int x = __shfl_up(v, o, 64);
        if (lane >= o) v += x;
    }
    return v;
}

__global__ void k_bsum(const int* __restrict__ degI, int* __restrict__ bsum) {
    int i = blockIdx.x * 256 + threadIdx.x;
    int v = (i < NN) ? degI[i] : 0;
#pragma unroll
    for (int o = 32; o >= 1; o >>= 1) v += __shfl_xor(v, o, 64);
    __shared__ int ws[4];
    if ((threadIdx.x & 63) == 0) ws[threadIdx.x >> 6] = v;
    __syncthreads();
    if (threadIdx.x == 0) bsum[blockIdx.x] = ws[0] + ws[1] + ws[2] + ws[3];
}

__global__ void k_bscan(const int* __restrict__ bsum, int* __restrict__ bofs) {
    int t = threadIdx.x;                 // single block of 256
    int v = (t < NBLK) ? bsum[t] : 0;
    int lane = t & 63, w = t >> 6;
    int inc = wave_iscan(v, lane);
    __shared__ int ws[4];
    if (lane == 63) ws[w] = inc;
    __syncthreads();
    int add = 0;
    for (int i = 0; i < w; i++) add += ws[i];
    if (t < NBLK) bofs[t] = add + inc - v;
}

__global__ void k_rowptr(const int* __restrict__ degI, const int* __restrict__ bofs,
                         int* __restrict__ rowptr) {
    int i = blockIdx.x * 256 + threadIdx.x;
    int v = (i < NN) ? degI[i] : 0;
    int lane = threadIdx.x & 63, w = threadIdx.x >> 6;
    int inc = wave_iscan(v, lane);
    __shared__ int ws[4];
    if (lane == 63) ws[w] = inc;
    __syncthreads();
    int add = 0;
    for (int k = 0; k < w; k++) add += ws[k];
    if (i < NN) rowptr[i] = bofs[blockIdx.x] + add + inc - v;
    if (i == 0) rowptr[NN] = NE;
}

__global__ void k_sort(const int* __restrict__ src, const int* __restrict__ dst,
                       const int* __restrict__ rowptr, int* __restrict__ fill,
                       int* __restrict__ eidx) {
    int e = blockIdx.x * 256 + threadIdx.x;
    if (e < NE) {
        int d = dst[e];
        int p = rowptr[d] + atomicAdd(&fill[d], 1);
        eidx[p] = src[e];
    }
}

// ---------------- bf16 conversions ----------------
__global__ void k_cvtW(const float* __restrict__ W, unsigned short* __restrict__ Wb, int n) {
    int i = blockIdx.x * 256 + threadIdx.x;
    if (i < n) Wb[i] = f2bf(W[i]);
}

__global__ void k_cvt0(const float* __restrict__ x, const float* __restrict__ nS,
                       unsigned short* __restrict__ xb) {
    int row = blockIdx.x; int t = threadIdx.x;
    if (row < NN) {
        float s = nS[row];
        xb[(long)row * 256 + t] = f2bf(x[(long)row * 256 + t] * s);
    } else {
        xb[(long)row * 256 + t] = 0;
    }
}

// ---------------- GEMM (unchanged from R1, correctness-verified) ----------------
template<int NOUT>
__global__ __launch_bounds__(256) void k_gemm(const unsigned short* __restrict__ A,
                                              const unsigned short* __restrict__ B,
                                              float* __restrict__ C) {
    __shared__ unsigned short As[128][40];
    __shared__ unsigned short Bs[128][40];
    const int bm = blockIdx.x * 128;
    const int bn = blockIdx.y * 128;
    const int tid = threadIdx.x;
    const int lane = tid & 63;
    const int w = tid >> 6;
    const int wr = w >> 1, wc = w & 1;

    f32x4 acc[4][4];
#pragma unroll
    for (int m = 0; m < 4; m++)
#pragma unroll
        for (int n = 0; n < 4; n++) acc[m][n] = (f32x4){0.f, 0.f, 0.f, 0.f};

    for (int kt = 0; kt < 256; kt += 32) {
        {
            int r = tid >> 1, c = (tid & 1) * 16;
            const unsigned short* g = &A[(long)(bm + r) * 256 + kt + c];
            *(us8*)&As[r][c]     = *(const us8*)(g);
            *(us8*)&As[r][c + 8] = *(const us8*)(g + 8);
        }
        {
            int k = tid >> 3, c0 = (tid & 7) * 16;
            const unsigned short* g = &B[(long)(kt + k) * NOUT + bn + c0];
            us8 v0 = *(const us8*)(g);
            us8 v1 = *(const us8*)(g + 8);
#pragma unroll
            for (int j = 0; j < 8; j++) Bs[c0 + j][k] = v0[j];
#pragma unroll
            for (int j = 0; j < 8; j++) Bs[c0 + 8 + j][k] = v1[j];
        }
        __syncthreads();

        union U { us4 h[2]; short8 s; };
        const int kb = (lane >> 4) * 4;
        short8 af[4], bf[4];
#pragma unroll
        for (int m = 0; m < 4; m++) {
            int r = wr * 64 + m * 16 + (lane & 15);
            U u; u.h[0] = *(const us4*)&As[r][kb]; u.h[1] = *(const us4*)&As[r][kb + 16];
            af[m] = u.s;
        }
#pragma unroll
        for (int n = 0; n < 4; n++) {
            int cidx = wc * 64 + n * 16 + (lane & 15);
            U u; u.h[0] = *(const us4*)&Bs[cidx][kb]; u.h[1] = *(const us4*)&Bs[cidx][kb + 16];
            bf[n] = u.s;
        }
#pragma unroll
        for (int m = 0; m < 4; m++)
#pragma unroll
            for (int n = 0; n < 4; n++)
                acc[m][n] = __builtin_amdgcn_mfma_f32_16x16x32_bf16(af[m], bf[n], acc[m][n], 0, 0, 0);
        __syncthreads();
    }

#pragma unroll
    for (int m = 0; m < 4; m++) {
        int rbase = bm + wr * 64 + m * 16 + (lane >> 4) * 4;
#pragma unroll
        for (int n = 0; n < 4; n++) {
            int cidx = bn + wc * 64 + n * 16 + (lane & 15);
#pragma unroll
            for (int j = 0; j < 4; j++)
                C[(long)(rbase + j) * NOUT + cidx] = acc[m][n][j];
        }
    }
}

// ---------------- CSR gather-aggregate, fused epilogue ----------------
// one wave per dst node; lane owns F/64 consecutive floats.
// out = (sum_{e in CSR[node]} hg[src_e]) * nD + b (+relu); optional dup; optional next xb.
template<int F, bool RELU, bool NEXT>
__global__ __launch_bounds__(256) void k_agg(const int* __restrict__ rowptr,
                                             const int* __restrict__ eidx,
                                             const float* __restrict__ hg,
                                             const float* __restrict__ nD,
                                             const float* __restrict__ nS,
                                             const float* __restrict__ b,
                                             float* __restrict__ out,
                                             float* __restrict__ out2,
                                             unsigned short* __restrict__ xb) {
    const int node = blockIdx.x * 4 + (threadIdx.x >> 6);
    const int lane = threadIdx.x & 63;
    if (node >= NN) {
        if (NEXT && node < MPAD) {   // zero GEMM pad rows of next-layer input
            int c = lane * 4;
            *(us4*)&xb[(long)node * 256 + c] = (us4){0, 0, 0, 0};
        }
        return;
    }
    constexpr int V = F / 64;        // 4 (F=256) or 2 (F=128)
    const int c = lane * V;
    const int e0 = rowptr[node], e1 = rowptr[node + 1];

    if (F == 256) {
        f32x4 a0 = {0.f, 0.f, 0.f, 0.f}, a1 = {0.f, 0.f, 0.f, 0.f};
        int j = e0;
        for (; j + 2 <= e1; j += 2) {
            int s0 = eidx[j], s1 = eidx[j + 1];
            a0 += *(const f32x4*)&hg[(long)s0 * 256 + c];
            a1 += *(const f32x4*)&hg[(long)s1 * 256 + c];
        }
        if (j < e1) a0 += *(const f32x4*)&hg[(long)eidx[j] * 256 + c];
        f32x4 s = a0 + a1;
        float nd = nD[node];
        f32x4 bb = *(const f32x4*)&b[c];
        f32x4 v = s * nd + bb;
        if (RELU) {
#pragma unroll
            for (int k = 0; k < 4; k++) v[k] = fmaxf(v[k], 0.f);
        }
        *(f32x4*)&out[(long)node * 256 + c] = v;
        if (NEXT) {
            float ns = nS[node];
            us4 o;
#pragma unroll
            for (int k = 0; k < 4; k++) o[k] = f2bf(v[k] * ns);
            *(us4*)&xb[(long)node * 256 + c] = o;
        }
    } else {
        f32x2 a0 = {0.f, 0.f}, a1 = {0.f, 0.f};
        int j = e0;
        for (; j + 2 <= e1; j += 2) {
            int s0 = eidx[j], s1 = eidx[j + 1];
            a0 += *(const f32x2*)&hg[(long)s0 * 128 + c];
            a1 += *(const f32x2*)&hg[(long)s1 * 128 + c];
        }
        if (j < e1) a0 += *(const f32x2*)&hg[(long)eidx[j] * 128 + c];
        f32x2 s = a0 + a1;
        float nd = nD[node];
        f32x2 bb = *(const f32x2*)&b[c];
        f32x2 v = s * nd + bb;
        if (RELU) {
            v[0] = fmaxf(v[0], 0.f); v[1] = fmaxf(v[1], 0.f);
        }
        *(f32x2*)&out[(long)node * 128 + c] = v;
        if (out2) *(f32x2*)&out2[(long)node * 128 + c] = v;
    }
}

extern "C" void kernel_launch(void* const* d_in, const int* in_sizes, int n_in,
                              void* d_out, int out_size, void* d_ws, size_t ws_size,
                              hipStream_t stream) {
    const float* feats = (const float*)d_in[0];
    const int*   src   = (const int*)d_in[1];
    const int*   dst   = (const int*)d_in[2];
    const float* W0 = (const float*)d_in[3];
    const float* b0 = (const float*)d_in[4];
    const float* W1 = (const float*)d_in[5];
    const float* b1 = (const float*)d_in[6];
    const float* W2 = (const float*)d_in[7];
    const float* b2 = (const float*)d_in[8];

    float* out = (float*)d_out;
    float* h0  = out;
    float* h1  = out + (long)NN * 256;
    float* h2  = out + 2L * NN * 256;
    float* h2b = out + 2L * NN * 256 + (long)NN * 128;

    char* ws = (char*)d_ws;
    size_t off = 0;
    auto alloc = [&](size_t bytes) { void* p = ws + off; off += (bytes + 255) & ~255UL; return p; };
    unsigned short* xb  = (unsigned short*)alloc((size_t)MPAD * 256 * 2);
    float* hg   = (float*)alloc((size_t)MPAD * 256 * 4);
    unsigned short* W0b = (unsigned short*)alloc(256 * 256 * 2);
    unsigned short* W1b = (unsigned short*)alloc(256 * 256 * 2);
    unsigned short* W2b = (unsigned short*)alloc(256 * 128 * 2);
    int*   degO   = (int*)alloc(NN * 4);
    int*   degI   = (int*)alloc(NN * 4);
    float* nS     = (float*)alloc(NN * 4);
    float* nD     = (float*)alloc(NN * 4);
    int*   rowptr = (int*)alloc((NN + 1) * 4);
    int*   bsum   = (int*)alloc(NBLK * 4);
    int*   bofs   = (int*)alloc(NBLK * 4);
    int*   fill   = (int*)alloc(NN * 4);
    int*   eidx   = (int*)alloc((size_t)NE * 4);

    // degrees + norms
    hipMemsetAsync(degO, 0, NN * 4, stream);
    hipMemsetAsync(degI, 0, NN * 4, stream);
    hipMemsetAsync(fill, 0, NN * 4, stream);
    k_deg<<<(NE + 255) / 256, 256, 0, stream>>>(src, dst, degO, degI);
    k_norm<<<(NN + 255) / 256, 256, 0, stream>>>(degO, degI, nS, nD);

    // CSR (by dst) — built once, reused by all 3 layers
    k_bsum<<<NBLK, 256, 0, stream>>>(degI, bsum);
    k_bscan<<<1, 256, 0, stream>>>(bsum, bofs);
    k_rowptr<<<NBLK, 256, 0, stream>>>(degI, bofs, rowptr);
    k_sort<<<(NE + 255) / 256, 256, 0, stream>>>(src, dst, rowptr, fill, eidx);

    // weight conversion
    k_cvtW<<<(256 * 256 + 255) / 256, 256, 0, stream>>>(W0, W0b, 256 * 256);
    k_cvtW<<<(256 * 256 + 255) / 256, 256, 0, stream>>>(W1, W1b, 256 * 256);
    k_cvtW<<<(256 * 128 + 255) / 256, 256, 0, stream>>>(W2, W2b, 256 * 128);

    // layer 0 input
    k_cvt0<<<MPAD, 256, 0, stream>>>(feats, nS, xb);

    // ---- layer 0 ----
    k_gemm<256><<<dim3(MPAD / 128, 2), 256, 0, stream>>>(xb, W0b, hg);
    k_agg<256, true, true><<<MPAD / 4, 256, 0, stream>>>(rowptr, eidx, hg, nD, nS, b0, h0, nullptr, xb);

    // ---- layer 1 ----
    k_gemm<256><<<dim3(MPAD / 128, 2), 256, 0, stream>>>(xb, W1b, hg);
    k_agg<256, true, true><<<MPAD / 4, 256, 0, stream>>>(rowptr, eidx, hg, nD, nS, b1, h1, nullptr, xb);

    // ---- layer 2 ----
    k_gemm<128><<<dim3(MPAD / 128, 1), 256, 0, stream>>>(xb, W2b, hg);
    k_agg<128, false, false><<<(NN + 3) / 4, 256, 0, stream>>>(rowptr, eidx, hg, nD, nS, b2, h2, h2b, nullptr);
}

// Round 3
// 424.284 us; speedup vs baseline: 16.3766x; 1.2952x over previous
//
#include <hip/hip_runtime.h>
#include <hip/hip_bf16.h>

#define NN 50000
#define NE 800000
#define MPAD 50048   // 391 * 128
#define NBLK 196     // ceil(NN/256)

typedef __attribute__((ext_vector_type(8))) short short8;
typedef __attribute__((ext_vector_type(4))) float f32x4;
typedef __attribute__((ext_vector_type(2))) float f32x2;
typedef __attribute__((ext_vector_type(2))) unsigned short us2;
typedef __attribute__((ext_vector_type(4))) unsigned short us4;
typedef __attribute__((ext_vector_type(8))) unsigned short us8;

static __device__ __forceinline__ unsigned short f2bf(float f) {
    union { float f; unsigned int u; } v; v.f = f;
    unsigned int u = v.u;
    return (unsigned short)((u + 0x7FFFu + ((u >> 16) & 1u)) >> 16);  // RNE
}
static __device__ __forceinline__ float bf2f(unsigned short h) {
    union { unsigned int u; float f; } v; v.u = ((unsigned int)h) << 16;
    return v.f;
}

// ---------------- degrees / norms ----------------
__global__ void k_deg(const int* __restrict__ src, const int* __restrict__ dst,
                      int* __restrict__ degO, int* __restrict__ degI) {
    int i = blockIdx.x * 256 + threadIdx.x;
    if (i < NE) {
        atomicAdd(&degO[src[i]], 1);
        atomicAdd(&degI[dst[i]], 1);
    }
}

__global__ void k_norm(const int* __restrict__ degO, const int* __restrict__ degI,
                       float* __restrict__ nS, float* __restrict__ nD) {
    int i = blockIdx.x * 256 + threadIdx.x;
    if (i < NN) {
        int o = degO[i], d = degI[i];
        nS[i] = 1.0f / sqrtf((float)(o > 0 ? o : 1));
        nD[i] = 1.0f / sqrtf((float)(d > 0 ? d : 1));
    }
}

// ---------------- CSR build ----------------
static __device__ __forceinline__ int wave_iscan(int v, int lane) {
#pragma unroll
    for (int o = 1; o < 64; o <<= 1) {
        int x = __shfl_up(v, o, 64);
        if (lane >= o) v += x;
    }
    return v;
}

__global__ void k_bsum(const int* __restrict__ degI, int* __restrict__ bsum) {
    int i = blockIdx.x * 256 + threadIdx.x;
    int v = (i < NN) ? degI[i] : 0;
#pragma unroll
    for (int o = 32; o >= 1; o >>= 1) v += __shfl_xor(v, o, 64);
    __shared__ int ws[4];
    if ((threadIdx.x & 63) == 0) ws[threadIdx.x >> 6] = v;
    __syncthreads();
    if (threadIdx.x == 0) bsum[blockIdx.x] = ws[0] + ws[1] + ws[2] + ws[3];
}

__global__ void k_bscan(const int* __restrict__ bsum, int* __restrict__ bofs) {
    int t = threadIdx.x;
    int v = (t < NBLK) ? bsum[t] : 0;
    int lane = t & 63, w = t >> 6;
    int inc = wave_iscan(v, lane);
    __shared__ int ws[4];
    if (lane == 63) ws[w] = inc;
    __syncthreads();
    int add = 0;
    for (int i = 0; i < w; i++) add += ws[i];
    if (t < NBLK) bofs[t] = add + inc - v;
}

__global__ void k_rowptr(const int* __restrict__ degI, const int* __restrict__ bofs,
                         int* __restrict__ rowptr) {
    int i = blockIdx.x * 256 + threadIdx.x;
    int v = (i < NN) ? degI[i] : 0;
    int lane = threadIdx.x & 63, w = threadIdx.x >> 6;
    int inc = wave_iscan(v, lane);
    __shared__ int ws[4];
    if (lane == 63) ws[w] = inc;
    __syncthreads();
    int add = 0;
    for (int k = 0; k < w; k++) add += ws[k];
    if (i < NN) rowptr[i] = bofs[blockIdx.x] + add + inc - v;
    if (i == 0) rowptr[NN] = NE;
}

__global__ void k_sort(const int* __restrict__ src, const int* __restrict__ dst,
                       const int* __restrict__ rowptr, int* __restrict__ fill,
                       int* __restrict__ eidx) {
    int e = blockIdx.x * 256 + threadIdx.x;
    if (e < NE) {
        int d = dst[e];
        int p = rowptr[d] + atomicAdd(&fill[d], 1);
        eidx[p] = src[e];
    }
}

// ---------------- bf16 conversions ----------------
__global__ void k_cvtW(const float* __restrict__ W, unsigned short* __restrict__ Wb, int n) {
    int i = blockIdx.x * 256 + threadIdx.x;
    if (i < n) Wb[i] = f2bf(W[i]);
}

__global__ void k_cvt0(const float* __restrict__ x, const float* __restrict__ nS,
                       unsigned short* __restrict__ xb) {
    int row = blockIdx.x; int t = threadIdx.x;
    if (row < NN) {
        float s = nS[row];
        xb[(long)row * 256 + t] = f2bf(x[(long)row * 256 + t] * s);
    } else {
        xb[(long)row * 256 + t] = 0;
    }
}

// ---------------- pre-GEMM aggregation (256-wide bf16), nD folded in ----------------
// one wave per dst node; lane owns 4 cols (8 B loads). aggb[node] = nD * sum xb[src].
__global__ __launch_bounds__(256) void k_aggb(const int* __restrict__ rowptr,
                                              const int* __restrict__ eidx,
                                              const unsigned short* __restrict__ xb,
                                              const float* __restrict__ nD,
                                              unsigned short* __restrict__ aggb) {
    const int node = blockIdx.x * 4 + (threadIdx.x >> 6);
    const int lane = threadIdx.x & 63;
    const int c = lane * 4;
    if (node >= NN) {
        if (node < MPAD) *(us4*)&aggb[(long)node * 256 + c] = (us4){0, 0, 0, 0};
        return;
    }
    const int e0 = rowptr[node], e1 = rowptr[node + 1];
    f32x4 acc = {0.f, 0.f, 0.f, 0.f};
    int j = e0;
    for (; j + 4 <= e1; j += 4) {
        int s0 = eidx[j], s1 = eidx[j + 1], s2 = eidx[j + 2], s3 = eidx[j + 3];
        us4 v0 = *(const us4*)&xb[(long)s0 * 256 + c];
        us4 v1 = *(const us4*)&xb[(long)s1 * 256 + c];
        us4 v2 = *(const us4*)&xb[(long)s2 * 256 + c];
        us4 v3 = *(const us4*)&xb[(long)s3 * 256 + c];
#pragma unroll
        for (int k = 0; k < 4; k++)
            acc[k] += (bf2f(v0[k]) + bf2f(v1[k])) + (bf2f(v2[k]) + bf2f(v3[k]));
    }
    for (; j < e1; j++) {
        us4 v = *(const us4*)&xb[(long)eidx[j] * 256 + c];
#pragma unroll
        for (int k = 0; k < 4; k++) acc[k] += bf2f(v[k]);
    }
    float nd = nD[node];
    us4 o;
#pragma unroll
    for (int k = 0; k < 4; k++) o[k] = f2bf(acc[k] * nd);
    *(us4*)&aggb[(long)node * 256 + c] = o;
}

// ---------------- GEMM: A [MPAD][256] bf16, B [256][NOUT] bf16 ----------------
// MODE 0: out = relu(acc + b) -> outF f32 (row<NN); xbn = f2bf(out*nS) (pad rows -> 0)
// MODE 1: outB = f2bf(acc)   (raw, no bias)
template<int NOUT, int MODE>
__global__ __launch_bounds__(256) void k_gemm(const unsigned short* __restrict__ A,
                                              const unsigned short* __restrict__ B,
                                              const float* __restrict__ bias,
                                              const float* __restrict__ nS,
                                              float* __restrict__ outF,
                                              unsigned short* __restrict__ xbn,
                                              unsigned short* __restrict__ outB) {
    __shared__ unsigned short As[128][40];
    __shared__ unsigned short Bs[128][40];
    const int bm = blockIdx.x * 128;
    const int bn = blockIdx.y * 128;
    const int tid = threadIdx.x;
    const int lane = tid & 63;
    const int w = tid >> 6;
    const int wr = w >> 1, wc = w & 1;

    f32x4 acc[4][4];
#pragma unroll
    for (int m = 0; m < 4; m++)
#pragma unroll
        for (int n = 0; n < 4; n++) acc[m][n] = (f32x4){0.f, 0.f, 0.f, 0.f};

    for (int kt = 0; kt < 256; kt += 32) {
        {
            int r = tid >> 1, c = (tid & 1) * 16;
            const unsigned short* g = &A[(long)(bm + r) * 256 + kt + c];
            *(us8*)&As[r][c]     = *(const us8*)(g);
            *(us8*)&As[r][c + 8] = *(const us8*)(g + 8);
        }
        {
            int k = tid >> 3, c0 = (tid & 7) * 16;
            const unsigned short* g = &B[(long)(kt + k) * NOUT + bn + c0];
            us8 v0 = *(const us8*)(g);
            us8 v1 = *(const us8*)(g + 8);
#pragma unroll
            for (int j = 0; j < 8; j++) Bs[c0 + j][k] = v0[j];
#pragma unroll
            for (int j = 0; j < 8; j++) Bs[c0 + 8 + j][k] = v1[j];
        }
        __syncthreads();

        union U { us4 h[2]; short8 s; };
        const int kb = (lane >> 4) * 4;
        short8 af[4], bf[4];
#pragma unroll
        for (int m = 0; m < 4; m++) {
            int r = wr * 64 + m * 16 + (lane & 15);
            U u; u.h[0] = *(const us4*)&As[r][kb]; u.h[1] = *(const us4*)&As[r][kb + 16];
            af[m] = u.s;
        }
#pragma unroll
        for (int n = 0; n < 4; n++) {
            int cidx = wc * 64 + n * 16 + (lane & 15);
            U u; u.h[0] = *(const us4*)&Bs[cidx][kb]; u.h[1] = *(const us4*)&Bs[cidx][kb + 16];
            bf[n] = u.s;
        }
#pragma unroll
        for (int m = 0; m < 4; m++)
#pragma unroll
            for (int n = 0; n < 4; n++)
                acc[m][n] = __builtin_amdgcn_mfma_f32_16x16x32_bf16(af[m], bf[n], acc[m][n], 0, 0, 0);
        __syncthreads();
    }

#pragma unroll
    for (int m = 0; m < 4; m++) {
        int rbase = bm + wr * 64 + m * 16 + (lane >> 4) * 4;
#pragma unroll
        for (int n = 0; n < 4; n++) {
            int cidx = bn + wc * 64 + n * 16 + (lane & 15);
            float bb = (MODE == 0) ? bias[cidx] : 0.f;
#pragma unroll
            for (int j = 0; j < 4; j++) {
                int row = rbase + j;
                float v = acc[m][n][j];
                if (MODE == 0) {
                    if (row < NN) {
                        v = fmaxf(v + bb, 0.f);
                        outF[(long)row * 256 + cidx] = v;
                        xbn[(long)row * 256 + cidx] = f2bf(v * nS[row]);
                    } else {
                        xbn[(long)row * 256 + cidx] = 0;
                    }
                } else {
                    outB[(long)row * NOUT + cidx] = f2bf(v);
                }
            }
        }
    }
}

// ---------------- layer-2 post-GEMM aggregation (128-wide bf16) ----------------
__global__ __launch_bounds__(256) void k_agg2(const int* __restrict__ rowptr,
                                              const int* __restrict__ eidx,
                                              const unsigned short* __restrict__ hgb,
                                              const float* __restrict__ nD,
                                              const float* __restrict__ b,
                                              float* __restrict__ h2,
                                              float* __restrict__ h2b) {
    const int node = blockIdx.x * 4 + (threadIdx.x >> 6);
    const int lane = threadIdx.x & 63;
    if (node >= NN) return;
    const int c = lane * 2;
    const int e0 = rowptr[node], e1 = rowptr[node + 1];
    f32x2 acc = {0.f, 0.f};
    int j = e0;
    for (; j + 4 <= e1; j += 4) {
        int s0 = eidx[j], s1 = eidx[j + 1], s2 = eidx[j + 2], s3 = eidx[j + 3];
        us2 v0 = *(const us2*)&hgb[(long)s0 * 128 + c];
        us2 v1 = *(const us2*)&hgb[(long)s1 * 128 + c];
        us2 v2 = *(const us2*)&hgb[(long)s2 * 128 + c];
        us2 v3 = *(const us2*)&hgb[(long)s3 * 128 + c];
#pragma unroll
        for (int k = 0; k < 2; k++)
            acc[k] += (bf2f(v0[k]) + bf2f(v1[k])) + (bf2f(v2[k]) + bf2f(v3[k]));
    }
    for (; j < e1; j++) {
        us2 v = *(const us2*)&hgb[(long)eidx[j] * 128 + c];
#pragma unroll
        for (int k = 0; k < 2; k++) acc[k] += bf2f(v[k]);
    }
    float nd = nD[node];
    f32x2 v;
    v[0] = acc[0] * nd + b[c];
    v[1] = acc[1] * nd + b[c + 1];
    *(f32x2*)&h2[(long)node * 128 + c] = v;
    *(f32x2*)&h2b[(long)node * 128 + c] = v;
}

extern "C" void kernel_launch(void* const* d_in, const int* in_sizes, int n_in,
                              void* d_out, int out_size, void* d_ws, size_t ws_size,
                              hipStream_t stream) {
    const float* feats = (const float*)d_in[0];
    const int*   src   = (const int*)d_in[1];
    const int*   dst   = (const int*)d_in[2];
    const float* W0 = (const float*)d_in[3];
    const float* b0 = (const float*)d_in[4];
    const float* W1 = (const float*)d_in[5];
    const float* b1 = (const float*)d_in[6];
    const float* W2 = (const float*)d_in[7];
    const float* b2 = (const float*)d_in[8];

    float* out = (float*)d_out;
    float* h0  = out;
    float* h1  = out + (long)NN * 256;
    float* h2  = out + 2L * NN * 256;
    float* h2b = out + 2L * NN * 256 + (long)NN * 128;

    char* ws = (char*)d_ws;
    size_t off = 0;
    auto alloc = [&](size_t bytes) { void* p = ws + off; off += (bytes + 255) & ~255UL; return p; };
    unsigned short* xb   = (unsigned short*)alloc((size_t)MPAD * 256 * 2);
    unsigned short* aggb = (unsigned short*)alloc((size_t)MPAD * 256 * 2);
    unsigned short* hgb  = (unsigned short*)alloc((size_t)MPAD * 128 * 2);
    unsigned short* W0b = (unsigned short*)alloc(256 * 256 * 2);
    unsigned short* W1b = (unsigned short*)alloc(256 * 256 * 2);
    unsigned short* W2b = (unsigned short*)alloc(256 * 128 * 2);
    int*   degO   = (int*)alloc(NN * 4);
    int*   degI   = (int*)alloc(NN * 4);
    float* nS     = (float*)alloc(NN * 4);
    float* nD     = (float*)alloc(NN * 4);
    int*   rowptr = (int*)alloc((NN + 1) * 4);
    int*   bsum   = (int*)alloc(NBLK * 4);
    int*   bofs   = (int*)alloc(NBLK * 4);
    int*   fill   = (int*)alloc(NN * 4);
    int*   eidx   = (int*)alloc((size_t)NE * 4);

    // degrees + norms
    hipMemsetAsync(degO, 0, NN * 4, stream);
    hipMemsetAsync(degI, 0, NN * 4, stream);
    hipMemsetAsync(fill, 0, NN * 4, stream);
    k_deg<<<(NE + 255) / 256, 256, 0, stream>>>(src, dst, degO, degI);
    k_norm<<<(NN + 255) / 256, 256, 0, stream>>>(degO, degI, nS, nD);

    // CSR (by dst)
    k_bsum<<<NBLK, 256, 0, stream>>>(degI, bsum);
    k_bscan<<<1, 256, 0, stream>>>(bsum, bofs);
    k_rowptr<<<NBLK, 256, 0, stream>>>(degI, bofs, rowptr);
    k_sort<<<(NE + 255) / 256, 256, 0, stream>>>(src, dst, rowptr, fill, eidx);

    // weights -> bf16
    k_cvtW<<<(256 * 256 + 255) / 256, 256, 0, stream>>>(W0, W0b, 256 * 256);
    k_cvtW<<<(256 * 256 + 255) / 256, 256, 0, stream>>>(W1, W1b, 256 * 256);
    k_cvtW<<<(256 * 128 + 255) / 256, 256, 0, stream>>>(W2, W2b, 256 * 128);

    // layer 0 input: xb = feats * nS (bf16)
    k_cvt0<<<MPAD, 256, 0, stream>>>(feats, nS, xb);

    // ---- layer 0: aggregate-first ----
    k_aggb<<<MPAD / 4, 256, 0, stream>>>(rowptr, eidx, xb, nD, aggb);
    k_gemm<256, 0><<<dim3(MPAD / 128, 2), 256, 0, stream>>>(aggb, W0b, b0, nS, h0, xb, nullptr);

    // ---- layer 1: aggregate-first ----
    k_aggb<<<MPAD / 4, 256, 0, stream>>>(rowptr, eidx, xb, nD, aggb);
    k_gemm<256, 0><<<dim3(MPAD / 128, 2), 256, 0, stream>>>(aggb, W1b, b1, nS, h1, xb, nullptr);

    // ---- layer 2: transform-first (gather 128-wide) ----
    k_gemm<128, 1><<<dim3(MPAD / 128, 1), 256, 0, stream>>>(xb, W2b, nullptr, nullptr, nullptr, nullptr, hgb);
    k_agg2<<<(NN + 3) / 4, 256, 0, stream>>>(rowptr, eidx, hgb, nD, b2, h2, h2b);
}